// Round 10
// baseline (940.687 us; speedup 1.0000x reference)
//
#include <hip/hip_runtime.h>
#include <hip/hip_bf16.h>

constexpr int HID = 256;
constexpr int NS = 7, NC = 2, NF = 9, HS = 50;
constexpr int BT  = 32;    // batch rows per block
constexpr int ROW = 264;   // bf16 row pitch for h buffer / w3t (528 B)
constexpr int NIP = 40;    // ni_bf row pitch in shorts (80 B, 16B-aligned)
constexpr float DT_C = 0.02f;

using short8 = __attribute__((ext_vector_type(8))) short;
using f32x4  = __attribute__((ext_vector_type(4))) float;

__device__ __forceinline__ unsigned short f2bf(float f) {
    unsigned int u = __float_as_uint(f);
    return (unsigned short)((u + 0x7FFFu + ((u >> 16) & 1u)) >> 16);   // RNE
}
__device__ __forceinline__ unsigned int pk2(float lo, float hi) {
    __hip_bfloat162 h = __float22bfloat162_rn(make_float2(lo, hi));
    return *reinterpret_cast<unsigned int*>(&h);
}
__device__ __forceinline__ float fast_tanh(float x) {
    // tanh(x) = 1 - 2/(e^{2x}+1); v_rcp_f32 forced via builtin (no IEEE div seq).
    float e = __expf(2.0f * x);
    return fmaf(-2.0f, __builtin_amdgcn_rcpf(e + 1.0f), 1.0f);
}

// Single h buffer (h1 then h2) + 64-VGPR cap -> ~29 KB LDS, 4 blocks/CU,
// grid 1024 = 4*256 exactly: no dispatch tail.
__global__ __launch_bounds__(512, 8)
void rollout_mfma6(const float* __restrict__ x,
                   const float* __restrict__ W1, const float* __restrict__ b1,
                   const float* __restrict__ W2, const float* __restrict__ b2,
                   const float* __restrict__ W3, const float* __restrict__ b3,
                   float* __restrict__ out)
{
    __shared__ __align__(16) unsigned short h[BT][ROW];     // h1, then h2
    __shared__ __align__(16) unsigned short w3t[16][ROW];   // W3^T, cols>=7 zero
    __shared__ __align__(16) unsigned short nibf[BT][NIP];  // [u0,u1,s0..6,1.0,0...]
    __shared__ __align__(16) float b2s[HID];

    const int tid  = threadIdx.x;
    const int w    = tid >> 6;        // wave 0..7, owns cols [w*32, w*32+32)
    const int lane = tid & 63;
    const int l15  = lane & 15;
    const int lg   = lane >> 4;
    const int b0   = blockIdx.x * BT;

    // ---- one-time: W2^T A-fragments (k = kb*32+lg*8+j, n = w*32+q*16+l15) ----
    short8 w2f[2][8];
    #pragma unroll
    for (int q = 0; q < 2; ++q) {
        const int n = w * 32 + q * 16 + l15;
        #pragma unroll
        for (int kb = 0; kb < 8; ++kb)
            #pragma unroll
            for (int j = 0; j < 8; ++j)
                w2f[q][kb][j] = (short)f2bf(W2[(kb * 32 + lg * 8 + j) * HID + n]);
    }
    // W1' A-fragments: rows 0..8 = W1, row 9 = b1 (bias via k), rows 10..31 = 0
    short8 w1f[2];
    #pragma unroll
    for (int q = 0; q < 2; ++q) {
        const int n = w * 32 + q * 16 + l15;
        #pragma unroll
        for (int j = 0; j < 8; ++j) {
            const int k = lg * 8 + j;
            float v = (k < NF) ? W1[k * HID + n] : (k == NF ? b1[n] : 0.0f);
            w1f[q][j] = (short)f2bf(v);
        }
    }
    float b3r[4];
    #pragma unroll
    for (int r = 0; r < 4; ++r) {
        const int s = lg * 4 + r;
        b3r[r] = (s < NS) ? b3[s] : 0.0f;
    }
    for (int i = tid; i < HID; i += 512) b2s[i] = b2[i];
    for (int i = tid; i < 16 * HID; i += 512) {
        const int s = i & 15, k = i >> 4;
        w3t[s][k] = (s < NS) ? f2bf(W3[k * NS + s]) : (unsigned short)0;
    }
    // net-in rows: x[b][0][0..8], bias-one at k=9, zeros above
    if (tid < BT) {
        const float* xp = &x[(b0 + tid) * (HS * NF)];
        #pragma unroll
        for (int k = 0; k < NIP; ++k) nibf[tid][k] = 0;
        #pragma unroll
        for (int f = 0; f < NF; ++f) nibf[tid][f] = f2bf(xp[f]);
        nibf[tid][NF] = f2bf(1.0f);
    }
    // master state in registers of waves 0,1: lane (l15,lg) owns b=w*16+l15, s=lg*4+r
    float st[4] = {0.f, 0.f, 0.f, 0.f};
    if (w < 2) {
        const int b = w * 16 + l15;
        #pragma unroll
        for (int r = 0; r < 4; ++r) {
            const int s = lg * 4 + r;
            if (s < NS) st[r] = x[(b0 + b) * (HS * NF) + NC + s];
        }
    }
    __syncthreads();

    for (int t = 0; t < HS; ++t) {
        // ---------- P1: h1 = tanh([ni,1] @ W1') via MFMA ----------
        f32x4 a1[2][2];
        #pragma unroll
        for (int q = 0; q < 2; ++q) { a1[q][0] = {0,0,0,0}; a1[q][1] = {0,0,0,0}; }
        #pragma unroll
        for (int bt = 0; bt < 2; ++bt) {
            short8 nf = *reinterpret_cast<const short8*>(&nibf[bt * 16 + l15][lg * 8]);
            #pragma unroll
            for (int q = 0; q < 2; ++q)
                a1[q][bt] = __builtin_amdgcn_mfma_f32_16x16x32_bf16(w1f[q], nf, a1[q][bt], 0, 0, 0);
        }
        #pragma unroll
        for (int q = 0; q < 2; ++q)
            #pragma unroll
            for (int bt = 0; bt < 2; ++bt) {
                uint2 pk;
                pk.x = pk2(fast_tanh(a1[q][bt][0]), fast_tanh(a1[q][bt][1]));
                pk.y = pk2(fast_tanh(a1[q][bt][2]), fast_tanh(a1[q][bt][3]));
                *reinterpret_cast<uint2*>(&h[bt * 16 + l15][w * 32 + q * 16 + lg * 4]) = pk;
            }
        __syncthreads();   // S1: h1 ready

        // ---------- P2: h2 = tanh(h1 @ W2 + b2) via MFMA (b2 in acc init) ----------
        f32x4 acc[2][2];
        #pragma unroll
        for (int q = 0; q < 2; ++q) {
            const float4 bv = *reinterpret_cast<const float4*>(&b2s[w * 32 + q * 16 + lg * 4]);
            f32x4 bi; bi[0] = bv.x; bi[1] = bv.y; bi[2] = bv.z; bi[3] = bv.w;
            acc[q][0] = bi; acc[q][1] = bi;
        }
        #pragma unroll
        for (int kb = 0; kb < 8; ++kb) {
            short8 h0  = *reinterpret_cast<const short8*>(&h[l15][kb * 32 + lg * 8]);
            short8 h1v = *reinterpret_cast<const short8*>(&h[16 + l15][kb * 32 + lg * 8]);
            #pragma unroll
            for (int q = 0; q < 2; ++q) {
                acc[q][0] = __builtin_amdgcn_mfma_f32_16x16x32_bf16(w2f[q][kb], h0,  acc[q][0], 0, 0, 0);
                acc[q][1] = __builtin_amdgcn_mfma_f32_16x16x32_bf16(w2f[q][kb], h1v, acc[q][1], 0, 0, 0);
            }
        }
        // tanh + pack into registers BEFORE the barrier (acc dies, pkv lives)
        uint2 pkv[2][2];
        #pragma unroll
        for (int q = 0; q < 2; ++q)
            #pragma unroll
            for (int bt = 0; bt < 2; ++bt) {
                pkv[q][bt].x = pk2(fast_tanh(acc[q][bt][0]), fast_tanh(acc[q][bt][1]));
                pkv[q][bt].y = pk2(fast_tanh(acc[q][bt][2]), fast_tanh(acc[q][bt][3]));
            }
        __syncthreads();   // S2a: all h1 reads complete, buffer reusable

        #pragma unroll
        for (int q = 0; q < 2; ++q)
            #pragma unroll
            for (int bt = 0; bt < 2; ++bt)
                *reinterpret_cast<uint2*>(&h[bt * 16 + l15][w * 32 + q * 16 + lg * 4]) = pkv[q][bt];
        __syncthreads();   // S2b: h2 ready

        // ---------- P3: d = h2 @ W3 + b3; state += DT*d (waves 0,1) ----------
        if (w < 2) {
            f32x4 a3 = {0.f, 0.f, 0.f, 0.f};
            #pragma unroll
            for (int kb = 0; kb < 8; ++kb) {
                short8 hv = *reinterpret_cast<const short8*>(&h[w * 16 + l15][kb * 32 + lg * 8]);
                short8 wf = *reinterpret_cast<const short8*>(&w3t[l15][kb * 32 + lg * 8]);
                a3 = __builtin_amdgcn_mfma_f32_16x16x32_bf16(wf, hv, a3, 0, 0, 0);
            }
            const int b = w * 16 + l15;
            float nsv[4];
            #pragma unroll
            for (int r = 0; r < 4; ++r) nsv[r] = st[r] + DT_C * (a3[r] + b3r[r]);
            if (lg == 0) {
                // s = 0..3 -> nibf shorts [2..5]
                st[0] = nsv[0]; st[1] = nsv[1]; st[2] = nsv[2]; st[3] = nsv[3];
                *reinterpret_cast<unsigned int*>(&nibf[b][2]) = pk2(nsv[0], nsv[1]);
                *reinterpret_cast<unsigned int*>(&nibf[b][4]) = pk2(nsv[2], nsv[3]);
                const int obase = (b0 + b) * (HS * NS) + t * NS;
                out[obase + 0] = nsv[0];
                out[obase + 1] = nsv[1];
                out[obase + 2] = nsv[2];
                out[obase + 3] = nsv[3];
            } else if (lg == 1) {
                // s = 4..6 -> nibf shorts [6..8]
                st[0] = nsv[0]; st[1] = nsv[1]; st[2] = nsv[2];
                *reinterpret_cast<unsigned int*>(&nibf[b][6]) = pk2(nsv[0], nsv[1]);
                nibf[b][8] = (unsigned short)pk2(nsv[2], nsv[2]);
                const int obase = (b0 + b) * (HS * NS) + t * NS;
                out[obase + 4] = nsv[0];
                out[obase + 5] = nsv[1];
                out[obase + 6] = nsv[2];
            }
        } else if (w == 2) {
            // next-step controls -> nibf[b][0..1] (bf16)
            if (t + 1 < HS) {
                const int b = lane & 31, c = lane >> 5;
                nibf[b][c] = f2bf(x[(b0 + b) * (HS * NF) + (t + 1) * NF + c]);
            }
        }
        __syncthreads();   // S3: state/controls ready for next P1
    }
}

extern "C" void kernel_launch(void* const* d_in, const int* in_sizes, int n_in,
                              void* d_out, int out_size, void* d_ws, size_t ws_size,
                              hipStream_t stream) {
    const float* x  = (const float*)d_in[0];
    const float* W1 = (const float*)d_in[1];
    const float* b1 = (const float*)d_in[2];
    const float* W2 = (const float*)d_in[3];
    const float* b2 = (const float*)d_in[4];
    const float* W3 = (const float*)d_in[5];
    const float* b3 = (const float*)d_in[6];
    float* out = (float*)d_out;

    const int B = in_sizes[0] / (HS * NF);   // 32768
    dim3 grid(B / BT), block(512);
    hipLaunchKernelGGL(rollout_mfma6, grid, block, 0, stream,
                       x, W1, b1, W2, b2, W3, b3, out);
}

// Round 11
// 410.518 us; speedup vs baseline: 2.2915x; 2.2915x over previous
//
#include <hip/hip_runtime.h>
#include <hip/hip_bf16.h>

constexpr int HID = 256;
constexpr int NS = 7, NC = 2, NF = 9, HS = 50;
constexpr int BT  = 32;    // batch rows per block
constexpr int ROW = 264;   // bf16 row pitch for h buffer / w3t (528 B)
constexpr int NIP = 40;    // ni_bf row pitch in shorts (80 B, 16B-aligned)
constexpr float DT_C = 0.02f;

using short8 = __attribute__((ext_vector_type(8))) short;
using f32x4  = __attribute__((ext_vector_type(4))) float;

__device__ __forceinline__ unsigned short f2bf(float f) {
    unsigned int u = __float_as_uint(f);
    return (unsigned short)((u + 0x7FFFu + ((u >> 16) & 1u)) >> 16);   // RNE
}
__device__ __forceinline__ unsigned int pk2(float lo, float hi) {
    __hip_bfloat162 h = __float22bfloat162_rn(make_float2(lo, hi));
    return *reinterpret_cast<unsigned int*>(&h);
}
__device__ __forceinline__ float fast_tanh(float x) {
    // tanh(x) = 1 - 2/(e^{2x}+1); v_rcp_f32 forced via builtin (no IEEE div seq).
    float e = __expf(2.0f * x);
    return fmaf(-2.0f, __builtin_amdgcn_rcpf(e + 1.0f), 1.0f);
}

// Merged h buffer -> 29 KB LDS (fits 5 blocks/CU); launch_bounds(512,4) keeps
// the r8-proven 64-VGPR allocation (r10's (512,8) forced 32 VGPR -> 2.7 GB of
// spill traffic). With 64 VGPR + 29 KB the HW can pack 4 blocks/CU: grid
// 1024 = 4*256 exactly, no dispatch tail.
__global__ __launch_bounds__(512, 4)
void rollout_mfma7(const float* __restrict__ x,
                   const float* __restrict__ W1, const float* __restrict__ b1,
                   const float* __restrict__ W2, const float* __restrict__ b2,
                   const float* __restrict__ W3, const float* __restrict__ b3,
                   float* __restrict__ out)
{
    __shared__ __align__(16) unsigned short h[BT][ROW];     // h1, then h2
    __shared__ __align__(16) unsigned short w3t[16][ROW];   // W3^T, cols>=7 zero
    __shared__ __align__(16) unsigned short nibf[BT][NIP];  // [u0,u1,s0..6,1.0,0...]
    __shared__ __align__(16) float b2s[HID];

    const int tid  = threadIdx.x;
    const int w    = tid >> 6;        // wave 0..7, owns cols [w*32, w*32+32)
    const int lane = tid & 63;
    const int l15  = lane & 15;
    const int lg   = lane >> 4;
    const int b0   = blockIdx.x * BT;

    // ---- one-time: W2^T A-fragments (k = kb*32+lg*8+j, n = w*32+q*16+l15) ----
    short8 w2f[2][8];
    #pragma unroll
    for (int q = 0; q < 2; ++q) {
        const int n = w * 32 + q * 16 + l15;
        #pragma unroll
        for (int kb = 0; kb < 8; ++kb)
            #pragma unroll
            for (int j = 0; j < 8; ++j)
                w2f[q][kb][j] = (short)f2bf(W2[(kb * 32 + lg * 8 + j) * HID + n]);
    }
    // W1' A-fragments: rows 0..8 = W1, row 9 = b1 (bias via k), rows 10..31 = 0
    short8 w1f[2];
    #pragma unroll
    for (int q = 0; q < 2; ++q) {
        const int n = w * 32 + q * 16 + l15;
        #pragma unroll
        for (int j = 0; j < 8; ++j) {
            const int k = lg * 8 + j;
            float v = (k < NF) ? W1[k * HID + n] : (k == NF ? b1[n] : 0.0f);
            w1f[q][j] = (short)f2bf(v);
        }
    }
    float b3r[4];
    #pragma unroll
    for (int r = 0; r < 4; ++r) {
        const int s = lg * 4 + r;
        b3r[r] = (s < NS) ? b3[s] : 0.0f;
    }
    for (int i = tid; i < HID; i += 512) b2s[i] = b2[i];
    for (int i = tid; i < 16 * HID; i += 512) {
        const int s = i & 15, k = i >> 4;
        w3t[s][k] = (s < NS) ? f2bf(W3[k * NS + s]) : (unsigned short)0;
    }
    // net-in rows: x[b][0][0..8], bias-one at k=9, zeros above
    if (tid < BT) {
        const float* xp = &x[(b0 + tid) * (HS * NF)];
        #pragma unroll
        for (int k = 0; k < NIP; ++k) nibf[tid][k] = 0;
        #pragma unroll
        for (int f = 0; f < NF; ++f) nibf[tid][f] = f2bf(xp[f]);
        nibf[tid][NF] = f2bf(1.0f);
    }
    // master state in registers of waves 0,1: lane (l15,lg) owns b=w*16+l15, s=lg*4+r
    float st[4] = {0.f, 0.f, 0.f, 0.f};
    if (w < 2) {
        const int b = w * 16 + l15;
        #pragma unroll
        for (int r = 0; r < 4; ++r) {
            const int s = lg * 4 + r;
            if (s < NS) st[r] = x[(b0 + b) * (HS * NF) + NC + s];
        }
    }
    __syncthreads();

    for (int t = 0; t < HS; ++t) {
        // ---------- P1: h1 = tanh([ni,1] @ W1') via MFMA ----------
        f32x4 a1[2][2];
        #pragma unroll
        for (int q = 0; q < 2; ++q) { a1[q][0] = {0,0,0,0}; a1[q][1] = {0,0,0,0}; }
        #pragma unroll
        for (int bt = 0; bt < 2; ++bt) {
            short8 nf = *reinterpret_cast<const short8*>(&nibf[bt * 16 + l15][lg * 8]);
            #pragma unroll
            for (int q = 0; q < 2; ++q)
                a1[q][bt] = __builtin_amdgcn_mfma_f32_16x16x32_bf16(w1f[q], nf, a1[q][bt], 0, 0, 0);
        }
        #pragma unroll
        for (int q = 0; q < 2; ++q)
            #pragma unroll
            for (int bt = 0; bt < 2; ++bt) {
                uint2 pk;
                pk.x = pk2(fast_tanh(a1[q][bt][0]), fast_tanh(a1[q][bt][1]));
                pk.y = pk2(fast_tanh(a1[q][bt][2]), fast_tanh(a1[q][bt][3]));
                *reinterpret_cast<uint2*>(&h[bt * 16 + l15][w * 32 + q * 16 + lg * 4]) = pk;
            }
        __syncthreads();   // S1: h1 ready

        // ---------- P2: h2 = tanh(h1 @ W2 + b2) via MFMA (b2 in acc init) ----------
        f32x4 acc[2][2];
        #pragma unroll
        for (int q = 0; q < 2; ++q) {
            const float4 bv = *reinterpret_cast<const float4*>(&b2s[w * 32 + q * 16 + lg * 4]);
            f32x4 bi; bi[0] = bv.x; bi[1] = bv.y; bi[2] = bv.z; bi[3] = bv.w;
            acc[q][0] = bi; acc[q][1] = bi;
        }
        #pragma unroll
        for (int kb = 0; kb < 8; ++kb) {
            short8 h0  = *reinterpret_cast<const short8*>(&h[l15][kb * 32 + lg * 8]);
            short8 h1v = *reinterpret_cast<const short8*>(&h[16 + l15][kb * 32 + lg * 8]);
            #pragma unroll
            for (int q = 0; q < 2; ++q) {
                acc[q][0] = __builtin_amdgcn_mfma_f32_16x16x32_bf16(w2f[q][kb], h0,  acc[q][0], 0, 0, 0);
                acc[q][1] = __builtin_amdgcn_mfma_f32_16x16x32_bf16(w2f[q][kb], h1v, acc[q][1], 0, 0, 0);
            }
        }
        // tanh + pack into registers BEFORE the barrier (acc dies, pkv lives)
        uint2 pkv[2][2];
        #pragma unroll
        for (int q = 0; q < 2; ++q)
            #pragma unroll
            for (int bt = 0; bt < 2; ++bt) {
                pkv[q][bt].x = pk2(fast_tanh(acc[q][bt][0]), fast_tanh(acc[q][bt][1]));
                pkv[q][bt].y = pk2(fast_tanh(acc[q][bt][2]), fast_tanh(acc[q][bt][3]));
            }
        __syncthreads();   // S2a: all h1 reads complete, buffer reusable

        #pragma unroll
        for (int q = 0; q < 2; ++q)
            #pragma unroll
            for (int bt = 0; bt < 2; ++bt)
                *reinterpret_cast<uint2*>(&h[bt * 16 + l15][w * 32 + q * 16 + lg * 4]) = pkv[q][bt];
        __syncthreads();   // S2b: h2 ready

        // ---------- P3: d = h2 @ W3 + b3; state += DT*d (waves 0,1) ----------
        if (w < 2) {
            f32x4 a3 = {0.f, 0.f, 0.f, 0.f};
            #pragma unroll
            for (int kb = 0; kb < 8; ++kb) {
                short8 hv = *reinterpret_cast<const short8*>(&h[w * 16 + l15][kb * 32 + lg * 8]);
                short8 wf = *reinterpret_cast<const short8*>(&w3t[l15][kb * 32 + lg * 8]);
                a3 = __builtin_amdgcn_mfma_f32_16x16x32_bf16(wf, hv, a3, 0, 0, 0);
            }
            const int b = w * 16 + l15;
            float nsv[4];
            #pragma unroll
            for (int r = 0; r < 4; ++r) nsv[r] = st[r] + DT_C * (a3[r] + b3r[r]);
            if (lg == 0) {
                // s = 0..3 -> nibf shorts [2..5]
                st[0] = nsv[0]; st[1] = nsv[1]; st[2] = nsv[2]; st[3] = nsv[3];
                *reinterpret_cast<unsigned int*>(&nibf[b][2]) = pk2(nsv[0], nsv[1]);
                *reinterpret_cast<unsigned int*>(&nibf[b][4]) = pk2(nsv[2], nsv[3]);
                const int obase = (b0 + b) * (HS * NS) + t * NS;
                out[obase + 0] = nsv[0];
                out[obase + 1] = nsv[1];
                out[obase + 2] = nsv[2];
                out[obase + 3] = nsv[3];
            } else if (lg == 1) {
                // s = 4..6 -> nibf shorts [6..8]
                st[0] = nsv[0]; st[1] = nsv[1]; st[2] = nsv[2];
                *reinterpret_cast<unsigned int*>(&nibf[b][6]) = pk2(nsv[0], nsv[1]);
                nibf[b][8] = (unsigned short)pk2(nsv[2], nsv[2]);
                const int obase = (b0 + b) * (HS * NS) + t * NS;
                out[obase + 4] = nsv[0];
                out[obase + 5] = nsv[1];
                out[obase + 6] = nsv[2];
            }
        } else if (w == 2) {
            // next-step controls -> nibf[b][0..1] (bf16)
            if (t + 1 < HS) {
                const int b = lane & 31, c = lane >> 5;
                nibf[b][c] = f2bf(x[(b0 + b) * (HS * NF) + (t + 1) * NF + c]);
            }
        }
        __syncthreads();   // S3: state/controls ready for next P1
    }
}

extern "C" void kernel_launch(void* const* d_in, const int* in_sizes, int n_in,
                              void* d_out, int out_size, void* d_ws, size_t ws_size,
                              hipStream_t stream) {
    const float* x  = (const float*)d_in[0];
    const float* W1 = (const float*)d_in[1];
    const float* b1 = (const float*)d_in[2];
    const float* W2 = (const float*)d_in[3];
    const float* b2 = (const float*)d_in[4];
    const float* W3 = (const float*)d_in[5];
    const float* b3 = (const float*)d_in[6];
    float* out = (float*)d_out;

    const int B = in_sizes[0] / (HS * NF);   // 32768
    dim3 grid(B / BT), block(512);
    hipLaunchKernelGGL(rollout_mfma7, grid, block, 0, stream,
                       x, W1, b1, W2, b2, W3, b3, out);
}